// Round 34
// baseline (453.499 us; speedup 1.0000x reference)
//
#include <hip/hip_runtime.h>

typedef _Float16 f16x8 __attribute__((ext_vector_type(8)));
typedef _Float16 f16x2 __attribute__((ext_vector_type(2)));
typedef float f32x4 __attribute__((ext_vector_type(4)));

#define NSUB 8      // sub-slots per bucket (blockIdx&7)
#define SCAP 768    // per-sub-slot capacity (mean 512 + 11 sigma)
#define BSH  8      // bucket shift: 256 nodes per bucket
#define BMSK 255u

__global__ void GraphCNN_48679159333670_kernel() {}

__device__ __forceinline__ int rdi(const int* p, int pos, int f64) {
    return f64 ? p[2 * pos] : p[pos];
}

__global__ void k_mark(float* out, float v) {
    int i = blockIdx.x * 64 + threadIdx.x;
    if (i < 1024) out[i] = v;
}
__global__ void k_detect(const int* ei, int* flag) {
    if (threadIdx.x == 0) {
        int nz = 0;
        for (int k = 0; k < 256; ++k) nz += (ei[2 * k + 1] != 0);
        flag[0] = (nz == 0);
    }
}
__global__ void k_zero(int* p, int n) {
    int i = blockIdx.x * 256 + threadIdx.x;
    if (i < n) p[i] = 0;
}
// scatter packed (s<<8)|(d&255) into per-(bucket,sub) slots. 256-node buckets:
// 3128 tails (~200KB hot) fill 8x faster -> less eviction between fills
__global__ void k_bscatter(const int* ei, int* bcur, unsigned* ebuf,
                           const int* flag, int ne, int nn, int nbk) {
    int i = blockIdx.x * 256 + threadIdx.x;
    int sub = blockIdx.x & (NSUB - 1);
    if (i < ne) {
        int f = flag[0];
        unsigned s = (unsigned)rdi(ei, i, f);
        unsigned d = (unsigned)rdi(ei, ne + i, f);
        if (s < (unsigned)nn && d < (unsigned)nn) {
            int slot = sub * nbk + (int)(d >> BSH);
            int p = atomicAdd(&bcur[slot], 1);
            if (p < SCAP) ebuf[(size_t)slot * SCAP + p] = (s << BSH) | (d & BMSK);
        }
    }
}
// one block (256 thr) per bucket: degree counts in LDS; cnt written dense
__global__ void k_bdeg(const unsigned* ebuf, const int* bcur, int* cnt,
                       int nbk, int nn) {
    __shared__ int lc[256];
    int b = blockIdx.x;
    int t = threadIdx.x;
    lc[t] = 0;
    __syncthreads();
    for (int sub = 0; sub < NSUB; ++sub) {
        int slot = sub * nbk + b;
        int n = bcur[slot];
        if (n > SCAP) n = SCAP;
        const unsigned* eb = ebuf + (size_t)slot * SCAP;
        for (int j = t; j < n; j += 256)
            atomicAdd(&lc[eb[j] & BMSK], 1);
    }
    __syncthreads();
    int node = (b << BSH) + t;
    if (node < nn) cnt[node] = lc[t];
}
__global__ void k_scan1(const int* cnt, int* rowp, int* bsum, float* dis, int nn) {
    __shared__ int s[256];
    int t = threadIdx.x;
    int i = blockIdx.x * 256 + t;
    int v = (i < nn) ? cnt[i] : 0;
    if (i < nn) dis[i] = rsqrtf((float)v + 1.0f);
    s[t] = v;
    __syncthreads();
    for (int off = 1; off < 256; off <<= 1) {
        int u = (t >= off) ? s[t - off] : 0;
        __syncthreads();
        s[t] += u;
        __syncthreads();
    }
    if (i < nn) rowp[i + 1] = s[t];
    if (t == 255) bsum[blockIdx.x] = s[t];
}
__global__ void k_scan2(int* bsum, int nb) {
    __shared__ int s[512];
    int t = threadIdx.x;
    s[t] = (t < nb) ? bsum[t] : 0;
    __syncthreads();
    for (int off = 1; off < 512; off <<= 1) {
        int u = (t >= off) ? s[t - off] : 0;
        __syncthreads();
        s[t] += u;
        __syncthreads();
    }
    if (t < nb) bsum[t] = s[t];
}
__global__ void k_scan3(int* rowp, const int* bsum, int nn) {
    int i = blockIdx.x * 256 + threadIdx.x;
    if (i == 0) rowp[0] = 0;
    if (i < nn) {
        int b = i >> 8;
        if (b > 0) rowp[i + 1] += bsum[b - 1];
    }
}
// one block (256 thr) per bucket: LDS cursors + row offsets; hot col window
__global__ void k_fill2(const unsigned* ebuf, const int* bcur, const int* rowp,
                        int* col, int nbk, int nn) {
    __shared__ int lcur[256];
    __shared__ int lrow[256];
    int b = blockIdx.x;
    int t = threadIdx.x;
    int node = (b << BSH) + t;
    lcur[t] = 0;
    lrow[t] = (node < nn) ? rowp[node] : 0;
    __syncthreads();
    for (int sub = 0; sub < NSUB; ++sub) {
        int slot = sub * nbk + b;
        int n = bcur[slot];
        if (n > SCAP) n = SCAP;
        const unsigned* eb = ebuf + (size_t)slot * SCAP;
        for (int j = t; j < n; j += 256) {
            unsigned e = eb[j];
            int loc = (int)(e & BMSK);
            int off = atomicAdd(&lcur[loc], 1);
            col[lrow[loc] + off] = (int)(e >> BSH);
        }
    }
}
__global__ void k_pack(const float* W, _Float16* Wp, int K) {
    int total = (K / 32) * 2048;
    int idx = blockIdx.x * 256 + threadIdx.x;
    if (idx < total) {
        int i = idx & 7;
        int lane = (idx >> 3) & 63;
        int w = (idx >> 9) & 3;
        int kk = idx >> 11;
        int k = kk * 32 + (lane >> 4) * 8 + i;
        int n = w * 16 + (lane & 15);
        Wp[idx] = (_Float16)W[k * 64 + n];
    }
}
// H' = (X @ W) * dis[node]
__global__ void k_mm_mfma(const float* X, const _Float16* Wp, _Float16* H,
                          const float* dis, int K) {
    int l = threadIdx.x & 63;
    int w = threadIdx.x >> 6;
    int n0 = blockIdx.x * 16;
    int am = l & 15;
    int kg = l >> 4;
    const float* xrow = X + (size_t)(n0 + am) * K + kg * 8;
    f32x4 acc = {0.f, 0.f, 0.f, 0.f};
    for (int kk = 0; kk < K / 32; ++kk) {
        const float4* xp = (const float4*)(xrow + kk * 32);
        float4 xa = xp[0];
        float4 xb = xp[1];
        f16x8 a = { (_Float16)xa.x, (_Float16)xa.y, (_Float16)xa.z, (_Float16)xa.w,
                    (_Float16)xb.x, (_Float16)xb.y, (_Float16)xb.z, (_Float16)xb.w };
        f16x8 b = *(const f16x8*)(Wp + ((size_t)(kk * 4 + w) * 64 + l) * 8);
        acc = __builtin_amdgcn_mfma_f32_16x16x32_f16(a, b, acc, 0, 0, 0);
    }
    int dn = w * 16 + (l & 15);
    int dm0 = (l >> 4) * 4;
#pragma unroll
    for (int r = 0; r < 4; ++r) {
        int node = n0 + dm0 + r;
        H[(size_t)node * 64 + dn] = (_Float16)(acc[r] * dis[node]);
    }
}
// O = relu((sum H'[s] + H'[i]) * dis[i] + b); 2 nodes/wave, 4x unroll
__global__ void k_agg(const _Float16* H, const int* col, const int* rowp,
                      const float* dis, const float* bias, float* O, int nn) {
    int hw = threadIdx.x >> 5;
    int lane = threadIdx.x & 31;
    int i = blockIdx.x * 8 + hw;
    if (i >= nn) return;
    const unsigned* Hu = (const unsigned*)H;
    int r0 = rowp[i], r1 = rowp[i + 1];
    float a0 = 0.f, a1 = 0.f;
    int j = r0;
    for (; j + 4 <= r1; j += 4) {
        int s0 = col[j + 0];
        int s1 = col[j + 1];
        int s2 = col[j + 2];
        int s3 = col[j + 3];
        unsigned u0 = Hu[(size_t)s0 * 32 + lane];
        unsigned u1 = Hu[(size_t)s1 * 32 + lane];
        unsigned u2 = Hu[(size_t)s2 * 32 + lane];
        unsigned u3 = Hu[(size_t)s3 * 32 + lane];
        f16x2 h0 = __builtin_bit_cast(f16x2, u0);
        f16x2 h1 = __builtin_bit_cast(f16x2, u1);
        f16x2 h2 = __builtin_bit_cast(f16x2, u2);
        f16x2 h3 = __builtin_bit_cast(f16x2, u3);
        a0 += (float)h0.x + (float)h1.x + (float)h2.x + (float)h3.x;
        a1 += (float)h0.y + (float)h1.y + (float)h2.y + (float)h3.y;
    }
    for (; j < r1; ++j) {
        int s = col[j];
        f16x2 h = __builtin_bit_cast(f16x2, Hu[(size_t)s * 32 + lane]);
        a0 += (float)h.x;
        a1 += (float)h.y;
    }
    f16x2 hi = __builtin_bit_cast(f16x2, Hu[(size_t)i * 32 + lane]);
    a0 += (float)hi.x;
    a1 += (float)hi.y;
    float di = dis[i];
    int ch = lane * 2;
    float2 o;
    o.x = fmaxf(a0 * di + bias[ch], 0.f);
    o.y = fmaxf(a1 * di + bias[ch + 1], 0.f);
    *(float2*)&O[(size_t)i * 64 + ch] = o;
}
// mean-pool: 16 nodes/wave, 4 waves/block; fast path for single-group chunks
__global__ void k_pool(const float* H, const int* batch, float* pool,
                       const int* flag, int nn) {
    int lane = threadIdx.x & 63;
    int w = threadIdx.x >> 6;
    int c0 = (blockIdx.x * 4 + w) * 16;
    if (c0 >= nn) return;
    int f = flag[0];
    int cend = c0 + 16;
    if (cend > nn) cend = nn;
    int g0 = rdi(batch, c0, f) & 63;
    int g1 = rdi(batch, cend - 1, f) & 63;
    if (g0 == g1) {
        float a0 = 0.f, a1 = 0.f, a2 = 0.f, a3 = 0.f;
        for (int i = c0; i + 4 <= cend; i += 4) {
            a0 += H[(size_t)(i + 0) * 64 + lane];
            a1 += H[(size_t)(i + 1) * 64 + lane];
            a2 += H[(size_t)(i + 2) * 64 + lane];
            a3 += H[(size_t)(i + 3) * 64 + lane];
        }
        atomicAdd(&pool[g0 * 64 + lane], (a0 + a1) + (a2 + a3));
        if (lane == 0) atomicAdd(&pool[4096 + g0], (float)(cend - c0));
    } else {
        float acc = 0.f, cf = 0.f;
        int curg = g0;
        for (int i = c0; i < cend; ++i) {
            int g = rdi(batch, i, f) & 63;
            if (g != curg) {
                atomicAdd(&pool[curg * 64 + lane], acc);
                if (lane == 0) atomicAdd(&pool[4096 + curg], cf);
                acc = 0.f; cf = 0.f; curg = g;
            }
            acc += H[(size_t)i * 64 + lane];
            cf += 1.f;
        }
        atomicAdd(&pool[curg * 64 + lane], acc);
        if (lane == 0) atomicAdd(&pool[4096 + curg], cf);
    }
}
__global__ void k_mlp(const float* pool, const float* fW1, const float* fb1,
                      const float* fW2, const float* fb2, float* out) {
    __shared__ float w1[2048], w2[512], b1s[32], b2s[16], gm[4096];
    int t = threadIdx.x;
    for (int i = t; i < 2048; i += 256) w1[i] = fW1[i];
    for (int i = t; i < 512; i += 256) w2[i] = fW2[i];
    if (t < 32) b1s[t] = fb1[t];
    if (t < 16) b2s[t] = fb2[t];
    for (int i = t; i < 4096; i += 256) {
        float c = pool[4096 + (i >> 6)];
        gm[i] = pool[i] / ((c < 1.f) ? 1.f : c);
    }
    __syncthreads();
    if (t < 64) {
        float hid[32], lg[16];
        for (int j = 0; j < 32; ++j) {
            float s = b1s[j];
            for (int k = 0; k < 64; ++k) s += gm[t * 64 + k] * w1[k * 32 + j];
            hid[j] = fmaxf(s, 0.f);
        }
        float m = -1e30f;
        for (int j = 0; j < 16; ++j) {
            float s = b2s[j];
            for (int k = 0; k < 32; ++k) s += hid[k] * w2[k * 16 + j];
            lg[j] = s;
            m = fmaxf(m, s);
        }
        float se = 0.f;
        for (int j = 0; j < 16; ++j) se += expf(lg[j] - m);
        float lse = m + logf(se);
        for (int j = 0; j < 16; ++j) out[t * 16 + j] = lg[j] - lse;
    }
}

extern "C" void kernel_launch(void* const* d_in, const int* in_sizes, int n_in,
                              void* d_out, int out_size, void* d_ws, size_t ws_size,
                              hipStream_t stream) {
    (void)in_sizes; (void)n_in; (void)out_size;
    const int nn = 100000, ne = 1600000;
    const int nbk = (nn + 255) / 256;   // 391 buckets of 256 nodes
    const float* x   = (const float*)d_in[0];
    const int*   ei  = (const int*)d_in[1];
    const int*   bat = (const int*)d_in[2];
    const float* W1  = (const float*)d_in[3];
    const float* b1  = (const float*)d_in[4];
    const float* W2  = (const float*)d_in[5];
    const float* b2  = (const float*)d_in[6];
    const float* W3  = (const float*)d_in[7];
    const float* b3  = (const float*)d_in[8];
    const float* fW1 = (const float*)d_in[9];
    const float* fb1 = (const float*)d_in[10];
    const float* fW2 = (const float*)d_in[11];
    const float* fb2 = (const float*)d_in[12];
    float* out = (float*)d_out;

    char* ws = (char*)d_ws;
    size_t o = 0;
    float*    pool = (float*)(ws + o);    o += 16896;
    int*      bcur = (int*)(ws + o);      o += 12800;    // 8*391*4 padded
    size_t zints = o / 4;
    int*      cnt  = (int*)(ws + o);      o += 400128;
    int*      rowp = (int*)(ws + o);      o += 400384;
    int*      bsum = (int*)(ws + o);      o += 2048;
    float*    dis  = (float*)(ws + o);    o += 400128;
    int*      flag = (int*)(ws + o);      o += 256;
    _Float16* Wp1  = (_Float16*)(ws + o); o += 16384;
    _Float16* Wp2  = (_Float16*)(ws + o); o += 8192;
    _Float16* Wp3  = (_Float16*)(ws + o); o += 8192;
    int*      col  = (int*)(ws + o);      o += 6400000;
    unsigned* ebuf = (unsigned*)(ws + o); o += (size_t)NSUB * nbk * SCAP * 4; // 9.6MB
    _Float16* A    = (_Float16*)(ws + o); o += 12800000;
    float*    B    = (float*)(ws + o);    o += 25600000;
    if (ws_size < o) {
        k_mark<<<16, 64, 0, stream>>>(out, 150.0f);
        return;
    }

    int eb = (ne + 255) / 256, nb = (nn + 255) / 256;
    int mmb = nn / 16;
    int aggb = (nn + 7) / 8;
    int poolb = (nn + 63) / 64;

    k_detect<<<1, 64, 0, stream>>>(ei, flag);
    k_zero<<<((int)zints + 255) / 256, 256, 0, stream>>>((int*)ws, (int)zints);
    k_bscatter<<<eb, 256, 0, stream>>>(ei, bcur, ebuf, flag, ne, nn, nbk);
    k_bdeg<<<nbk, 256, 0, stream>>>(ebuf, bcur, cnt, nbk, nn);
    k_scan1<<<nb, 256, 0, stream>>>(cnt, rowp, bsum, dis, nn);
    k_scan2<<<1, 512, 0, stream>>>(bsum, nb);
    k_scan3<<<nb, 256, 0, stream>>>(rowp, bsum, nn);
    k_fill2<<<nbk, 256, 0, stream>>>(ebuf, bcur, rowp, col, nbk, nn);

    k_pack<<<32, 256, 0, stream>>>(W1, Wp1, 128);
    k_pack<<<16, 256, 0, stream>>>(W2, Wp2, 64);
    k_pack<<<16, 256, 0, stream>>>(W3, Wp3, 64);

    k_mm_mfma<<<mmb, 256, 0, stream>>>(x, Wp1, A, dis, 128);
    k_agg<<<aggb, 256, 0, stream>>>(A, col, rowp, dis, b1, B, nn);
    k_mm_mfma<<<mmb, 256, 0, stream>>>(B, Wp2, A, dis, 64);
    k_agg<<<aggb, 256, 0, stream>>>(A, col, rowp, dis, b2, B, nn);
    k_mm_mfma<<<mmb, 256, 0, stream>>>(B, Wp3, A, dis, 64);
    k_agg<<<aggb, 256, 0, stream>>>(A, col, rowp, dis, b3, B, nn);

    k_pool<<<poolb, 256, 0, stream>>>(B, bat, pool, flag, nn);
    k_mlp<<<1, 256, 0, stream>>>(pool, fW1, fb1, fW2, fb2, out);
}

// Round 35
// 383.883 us; speedup vs baseline: 1.1813x; 1.1813x over previous
//
#include <hip/hip_runtime.h>

typedef _Float16 f16x8 __attribute__((ext_vector_type(8)));
typedef _Float16 f16x2 __attribute__((ext_vector_type(2)));
typedef float f32x4 __attribute__((ext_vector_type(4)));

#define NSUB 8      // sub-slots per bucket (blockIdx&7)
#define SCAP 256    // per-slot capacity: mean 128 + 11 sigma
#define BSH  6      // 64-node buckets: 12504 slots (contention/amplification balance)
#define BMSK 63u

__global__ void GraphCNN_48679159333670_kernel() {}

__device__ __forceinline__ int rdi(const int* p, int pos, int f64) {
    return f64 ? p[2 * pos] : p[pos];
}

__global__ void k_mark(float* out, float v) {
    int i = blockIdx.x * 64 + threadIdx.x;
    if (i < 1024) out[i] = v;
}
__global__ void k_detect(const int* ei, int* flag) {
    if (threadIdx.x == 0) {
        int nz = 0;
        for (int k = 0; k < 256; ++k) nz += (ei[2 * k + 1] != 0);
        flag[0] = (nz == 0);
    }
}
__global__ void k_zero(int* p, int n) {
    int i = blockIdx.x * 256 + threadIdx.x;
    if (i < n) p[i] = 0;
}
// scatter packed (s<<6)|(d&63) into per-(bucket,sub) slots
__global__ void k_bscatter(const int* ei, int* bcur, unsigned* ebuf,
                           const int* flag, int ne, int nn, int nbk) {
    int i = blockIdx.x * 256 + threadIdx.x;
    int sub = blockIdx.x & (NSUB - 1);
    if (i < ne) {
        int f = flag[0];
        unsigned s = (unsigned)rdi(ei, i, f);
        unsigned d = (unsigned)rdi(ei, ne + i, f);
        if (s < (unsigned)nn && d < (unsigned)nn) {
            int slot = sub * nbk + (int)(d >> BSH);
            int p = atomicAdd(&bcur[slot], 1);
            if (p < SCAP) ebuf[(size_t)slot * SCAP + p] = (s << BSH) | (d & BMSK);
        }
    }
}
// one wave per bucket: degree counts in LDS; cnt written dense
__global__ void k_bdeg(const unsigned* ebuf, const int* bcur, int* cnt,
                       int nbk, int nn) {
    __shared__ int lc[64];
    int b = blockIdx.x;
    int t = threadIdx.x;  // 64
    lc[t] = 0;
    __syncthreads();
    for (int sub = 0; sub < NSUB; ++sub) {
        int slot = sub * nbk + b;
        int n = bcur[slot];
        if (n > SCAP) n = SCAP;
        const unsigned* eb = ebuf + (size_t)slot * SCAP;
        for (int j = t; j < n; j += 64)
            atomicAdd(&lc[eb[j] & BMSK], 1);
    }
    __syncthreads();
    int node = (b << BSH) + t;
    if (node < nn) cnt[node] = lc[t];
}
__global__ void k_scan1(const int* cnt, int* rowp, int* bsum, float* dis, int nn) {
    __shared__ int s[256];
    int t = threadIdx.x;
    int i = blockIdx.x * 256 + t;
    int v = (i < nn) ? cnt[i] : 0;
    if (i < nn) dis[i] = rsqrtf((float)v + 1.0f);
    s[t] = v;
    __syncthreads();
    for (int off = 1; off < 256; off <<= 1) {
        int u = (t >= off) ? s[t - off] : 0;
        __syncthreads();
        s[t] += u;
        __syncthreads();
    }
    if (i < nn) rowp[i + 1] = s[t];
    if (t == 255) bsum[blockIdx.x] = s[t];
}
__global__ void k_scan2(int* bsum, int nb) {
    __shared__ int s[512];
    int t = threadIdx.x;
    s[t] = (t < nb) ? bsum[t] : 0;
    __syncthreads();
    for (int off = 1; off < 512; off <<= 1) {
        int u = (t >= off) ? s[t - off] : 0;
        __syncthreads();
        s[t] += u;
        __syncthreads();
    }
    if (t < nb) bsum[t] = s[t];
}
__global__ void k_scan3(int* rowp, const int* bsum, int nn) {
    int i = blockIdx.x * 256 + threadIdx.x;
    if (i == 0) rowp[0] = 0;
    if (i < nn) {
        int b = i >> 8;
        if (b > 0) rowp[i + 1] += bsum[b - 1];
    }
}
// one wave per bucket: LDS cursors + row offsets; hot col window
__global__ void k_fill2(const unsigned* ebuf, const int* bcur, const int* rowp,
                        int* col, int nbk, int nn) {
    __shared__ int lcur[64];
    __shared__ int lrow[64];
    int b = blockIdx.x;
    int t = threadIdx.x;  // 64
    int node = (b << BSH) + t;
    lcur[t] = 0;
    lrow[t] = (node < nn) ? rowp[node] : 0;
    __syncthreads();
    for (int sub = 0; sub < NSUB; ++sub) {
        int slot = sub * nbk + b;
        int n = bcur[slot];
        if (n > SCAP) n = SCAP;
        const unsigned* eb = ebuf + (size_t)slot * SCAP;
        for (int j = t; j < n; j += 64) {
            unsigned e = eb[j];
            int loc = (int)(e & BMSK);
            int off = atomicAdd(&lcur[loc], 1);
            col[lrow[loc] + off] = (int)(e >> BSH);
        }
    }
}
__global__ void k_pack(const float* W, _Float16* Wp, int K) {
    int total = (K / 32) * 2048;
    int idx = blockIdx.x * 256 + threadIdx.x;
    if (idx < total) {
        int i = idx & 7;
        int lane = (idx >> 3) & 63;
        int w = (idx >> 9) & 3;
        int kk = idx >> 11;
        int k = kk * 32 + (lane >> 4) * 8 + i;
        int n = w * 16 + (lane & 15);
        Wp[idx] = (_Float16)W[k * 64 + n];
    }
}
// H' = (X @ W) * dis[node]
__global__ void k_mm_mfma(const float* X, const _Float16* Wp, _Float16* H,
                          const float* dis, int K) {
    int l = threadIdx.x & 63;
    int w = threadIdx.x >> 6;
    int n0 = blockIdx.x * 16;
    int am = l & 15;
    int kg = l >> 4;
    const float* xrow = X + (size_t)(n0 + am) * K + kg * 8;
    f32x4 acc = {0.f, 0.f, 0.f, 0.f};
    for (int kk = 0; kk < K / 32; ++kk) {
        const float4* xp = (const float4*)(xrow + kk * 32);
        float4 xa = xp[0];
        float4 xb = xp[1];
        f16x8 a = { (_Float16)xa.x, (_Float16)xa.y, (_Float16)xa.z, (_Float16)xa.w,
                    (_Float16)xb.x, (_Float16)xb.y, (_Float16)xb.z, (_Float16)xb.w };
        f16x8 b = *(const f16x8*)(Wp + ((size_t)(kk * 4 + w) * 64 + l) * 8);
        acc = __builtin_amdgcn_mfma_f32_16x16x32_f16(a, b, acc, 0, 0, 0);
    }
    int dn = w * 16 + (l & 15);
    int dm0 = (l >> 4) * 4;
#pragma unroll
    for (int r = 0; r < 4; ++r) {
        int node = n0 + dm0 + r;
        H[(size_t)node * 64 + dn] = (_Float16)(acc[r] * dis[node]);
    }
}
// O = relu((sum H'[s] + H'[i]) * dis[i] + b); 2 nodes/wave, 4x unroll
__global__ void k_agg(const _Float16* H, const int* col, const int* rowp,
                      const float* dis, const float* bias, float* O, int nn) {
    int hw = threadIdx.x >> 5;
    int lane = threadIdx.x & 31;
    int i = blockIdx.x * 8 + hw;
    if (i >= nn) return;
    const unsigned* Hu = (const unsigned*)H;
    int r0 = rowp[i], r1 = rowp[i + 1];
    float a0 = 0.f, a1 = 0.f;
    int j = r0;
    for (; j + 4 <= r1; j += 4) {
        int s0 = col[j + 0];
        int s1 = col[j + 1];
        int s2 = col[j + 2];
        int s3 = col[j + 3];
        unsigned u0 = Hu[(size_t)s0 * 32 + lane];
        unsigned u1 = Hu[(size_t)s1 * 32 + lane];
        unsigned u2 = Hu[(size_t)s2 * 32 + lane];
        unsigned u3 = Hu[(size_t)s3 * 32 + lane];
        f16x2 h0 = __builtin_bit_cast(f16x2, u0);
        f16x2 h1 = __builtin_bit_cast(f16x2, u1);
        f16x2 h2 = __builtin_bit_cast(f16x2, u2);
        f16x2 h3 = __builtin_bit_cast(f16x2, u3);
        a0 += (float)h0.x + (float)h1.x + (float)h2.x + (float)h3.x;
        a1 += (float)h0.y + (float)h1.y + (float)h2.y + (float)h3.y;
    }
    for (; j < r1; ++j) {
        int s = col[j];
        f16x2 h = __builtin_bit_cast(f16x2, Hu[(size_t)s * 32 + lane]);
        a0 += (float)h.x;
        a1 += (float)h.y;
    }
    f16x2 hi = __builtin_bit_cast(f16x2, Hu[(size_t)i * 32 + lane]);
    a0 += (float)hi.x;
    a1 += (float)hi.y;
    float di = dis[i];
    int ch = lane * 2;
    float2 o;
    o.x = fmaxf(a0 * di + bias[ch], 0.f);
    o.y = fmaxf(a1 * di + bias[ch + 1], 0.f);
    *(float2*)&O[(size_t)i * 64 + ch] = o;
}
// mean-pool: 16 nodes/wave, 4 waves/block; fast path for single-group chunks
__global__ void k_pool(const float* H, const int* batch, float* pool,
                       const int* flag, int nn) {
    int lane = threadIdx.x & 63;
    int w = threadIdx.x >> 6;
    int c0 = (blockIdx.x * 4 + w) * 16;
    if (c0 >= nn) return;
    int f = flag[0];
    int cend = c0 + 16;
    if (cend > nn) cend = nn;
    int g0 = rdi(batch, c0, f) & 63;
    int g1 = rdi(batch, cend - 1, f) & 63;
    if (g0 == g1) {
        float a0 = 0.f, a1 = 0.f, a2 = 0.f, a3 = 0.f;
        for (int i = c0; i + 4 <= cend; i += 4) {
            a0 += H[(size_t)(i + 0) * 64 + lane];
            a1 += H[(size_t)(i + 1) * 64 + lane];
            a2 += H[(size_t)(i + 2) * 64 + lane];
            a3 += H[(size_t)(i + 3) * 64 + lane];
        }
        atomicAdd(&pool[g0 * 64 + lane], (a0 + a1) + (a2 + a3));
        if (lane == 0) atomicAdd(&pool[4096 + g0], (float)(cend - c0));
    } else {
        float acc = 0.f, cf = 0.f;
        int curg = g0;
        for (int i = c0; i < cend; ++i) {
            int g = rdi(batch, i, f) & 63;
            if (g != curg) {
                atomicAdd(&pool[curg * 64 + lane], acc);
                if (lane == 0) atomicAdd(&pool[4096 + curg], cf);
                acc = 0.f; cf = 0.f; curg = g;
            }
            acc += H[(size_t)i * 64 + lane];
            cf += 1.f;
        }
        atomicAdd(&pool[curg * 64 + lane], acc);
        if (lane == 0) atomicAdd(&pool[4096 + curg], cf);
    }
}
__global__ void k_mlp(const float* pool, const float* fW1, const float* fb1,
                      const float* fW2, const float* fb2, float* out) {
    __shared__ float w1[2048], w2[512], b1s[32], b2s[16], gm[4096];
    int t = threadIdx.x;
    for (int i = t; i < 2048; i += 256) w1[i] = fW1[i];
    for (int i = t; i < 512; i += 256) w2[i] = fW2[i];
    if (t < 32) b1s[t] = fb1[t];
    if (t < 16) b2s[t] = fb2[t];
    for (int i = t; i < 4096; i += 256) {
        float c = pool[4096 + (i >> 6)];
        gm[i] = pool[i] / ((c < 1.f) ? 1.f : c);
    }
    __syncthreads();
    if (t < 64) {
        float hid[32], lg[16];
        for (int j = 0; j < 32; ++j) {
            float s = b1s[j];
            for (int k = 0; k < 64; ++k) s += gm[t * 64 + k] * w1[k * 32 + j];
            hid[j] = fmaxf(s, 0.f);
        }
        float m = -1e30f;
        for (int j = 0; j < 16; ++j) {
            float s = b2s[j];
            for (int k = 0; k < 32; ++k) s += hid[k] * w2[k * 16 + j];
            lg[j] = s;
            m = fmaxf(m, s);
        }
        float se = 0.f;
        for (int j = 0; j < 16; ++j) se += expf(lg[j] - m);
        float lse = m + logf(se);
        for (int j = 0; j < 16; ++j) out[t * 16 + j] = lg[j] - lse;
    }
}

extern "C" void kernel_launch(void* const* d_in, const int* in_sizes, int n_in,
                              void* d_out, int out_size, void* d_ws, size_t ws_size,
                              hipStream_t stream) {
    (void)in_sizes; (void)n_in; (void)out_size;
    const int nn = 100000, ne = 1600000;
    const int nbk = (nn + 63) / 64;   // 1563 buckets of 64 nodes
    const float* x   = (const float*)d_in[0];
    const int*   ei  = (const int*)d_in[1];
    const int*   bat = (const int*)d_in[2];
    const float* W1  = (const float*)d_in[3];
    const float* b1  = (const float*)d_in[4];
    const float* W2  = (const float*)d_in[5];
    const float* b2  = (const float*)d_in[6];
    const float* W3  = (const float*)d_in[7];
    const float* b3  = (const float*)d_in[8];
    const float* fW1 = (const float*)d_in[9];
    const float* fb1 = (const float*)d_in[10];
    const float* fW2 = (const float*)d_in[11];
    const float* fb2 = (const float*)d_in[12];
    float* out = (float*)d_out;

    char* ws = (char*)d_ws;
    size_t o = 0;
    float*    pool = (float*)(ws + o);    o += 16896;
    int*      bcur = (int*)(ws + o);      o += 50176;    // 8*1563*4 padded
    size_t zints = o / 4;
    int*      cnt  = (int*)(ws + o);      o += 400128;
    int*      rowp = (int*)(ws + o);      o += 400384;
    int*      bsum = (int*)(ws + o);      o += 2048;
    float*    dis  = (float*)(ws + o);    o += 400128;
    int*      flag = (int*)(ws + o);      o += 256;
    _Float16* Wp1  = (_Float16*)(ws + o); o += 16384;
    _Float16* Wp2  = (_Float16*)(ws + o); o += 8192;
    _Float16* Wp3  = (_Float16*)(ws + o); o += 8192;
    int*      col  = (int*)(ws + o);      o += 6400000;
    unsigned* ebuf = (unsigned*)(ws + o); o += (size_t)NSUB * nbk * SCAP * 4; // 12.8MB
    _Float16* A    = (_Float16*)(ws + o); o += 12800000;
    float*    B    = (float*)(ws + o);    o += 25600000;
    if (ws_size < o) {
        k_mark<<<16, 64, 0, stream>>>(out, 150.0f);
        return;
    }

    int eb = (ne + 255) / 256, nb = (nn + 255) / 256;
    int mmb = nn / 16;
    int aggb = (nn + 7) / 8;
    int poolb = (nn + 63) / 64;

    k_detect<<<1, 64, 0, stream>>>(ei, flag);
    k_zero<<<((int)zints + 255) / 256, 256, 0, stream>>>((int*)ws, (int)zints);
    k_bscatter<<<eb, 256, 0, stream>>>(ei, bcur, ebuf, flag, ne, nn, nbk);
    k_bdeg<<<nbk, 64, 0, stream>>>(ebuf, bcur, cnt, nbk, nn);
    k_scan1<<<nb, 256, 0, stream>>>(cnt, rowp, bsum, dis, nn);
    k_scan2<<<1, 512, 0, stream>>>(bsum, nb);
    k_scan3<<<nb, 256, 0, stream>>>(rowp, bsum, nn);
    k_fill2<<<nbk, 64, 0, stream>>>(ebuf, bcur, rowp, col, nbk, nn);

    k_pack<<<32, 256, 0, stream>>>(W1, Wp1, 128);
    k_pack<<<16, 256, 0, stream>>>(W2, Wp2, 64);
    k_pack<<<16, 256, 0, stream>>>(W3, Wp3, 64);

    k_mm_mfma<<<mmb, 256, 0, stream>>>(x, Wp1, A, dis, 128);
    k_agg<<<aggb, 256, 0, stream>>>(A, col, rowp, dis, b1, B, nn);
    k_mm_mfma<<<mmb, 256, 0, stream>>>(B, Wp2, A, dis, 64);
    k_agg<<<aggb, 256, 0, stream>>>(A, col, rowp, dis, b2, B, nn);
    k_mm_mfma<<<mmb, 256, 0, stream>>>(B, Wp3, A, dis, 64);
    k_agg<<<aggb, 256, 0, stream>>>(A, col, rowp, dis, b3, B, nn);

    k_pool<<<poolb, 256, 0, stream>>>(B, bat, pool, flag, nn);
    k_mlp<<<1, 256, 0, stream>>>(pool, fW1, fb1, fW2, fb2, out);
}

// Round 36
// 377.694 us; speedup vs baseline: 1.2007x; 1.0164x over previous
//
#include <hip/hip_runtime.h>

typedef _Float16 f16x8 __attribute__((ext_vector_type(8)));
typedef _Float16 f16x2 __attribute__((ext_vector_type(2)));
typedef float f32x4 __attribute__((ext_vector_type(4)));

#define NSUB 8      // sub-slots per bucket (blockIdx&7)
#define SCAP 256    // per-slot capacity: mean 128 + 11 sigma
#define BSH  6      // 64-node buckets
#define BMSK 63u

__global__ void GraphCNN_48679159333670_kernel() {}

__device__ __forceinline__ int rdi(const int* p, int pos, int f64) {
    return f64 ? p[2 * pos] : p[pos];
}
// A-fragment load: f32 input (convert) or f16 input (direct 16B load)
__device__ __forceinline__ f16x8 load_a(const float* p) {
    const float4* q = (const float4*)p;
    float4 xa = q[0];
    float4 xb = q[1];
    f16x8 a = { (_Float16)xa.x, (_Float16)xa.y, (_Float16)xa.z, (_Float16)xa.w,
                (_Float16)xb.x, (_Float16)xb.y, (_Float16)xb.z, (_Float16)xb.w };
    return a;
}
__device__ __forceinline__ f16x8 load_a(const _Float16* p) {
    return *(const f16x8*)p;
}
// agg output store: f32 (float2) or f16 (f16x2)
__device__ __forceinline__ void store_o(float* p, float a, float b) {
    float2 o; o.x = a; o.y = b;
    *(float2*)p = o;
}
__device__ __forceinline__ void store_o(_Float16* p, float a, float b) {
    f16x2 h; h.x = (_Float16)a; h.y = (_Float16)b;
    *(f16x2*)p = h;
}

__global__ void k_mark(float* out, float v) {
    int i = blockIdx.x * 64 + threadIdx.x;
    if (i < 1024) out[i] = v;
}
__global__ void k_detect(const int* ei, int* flag) {
    if (threadIdx.x == 0) {
        int nz = 0;
        for (int k = 0; k < 256; ++k) nz += (ei[2 * k + 1] != 0);
        flag[0] = (nz == 0);
    }
}
__global__ void k_zero(int* p, int n) {
    int i = blockIdx.x * 256 + threadIdx.x;
    if (i < n) p[i] = 0;
}
__global__ void k_bscatter(const int* ei, int* bcur, unsigned* ebuf,
                           const int* flag, int ne, int nn, int nbk) {
    int i = blockIdx.x * 256 + threadIdx.x;
    int sub = blockIdx.x & (NSUB - 1);
    if (i < ne) {
        int f = flag[0];
        unsigned s = (unsigned)rdi(ei, i, f);
        unsigned d = (unsigned)rdi(ei, ne + i, f);
        if (s < (unsigned)nn && d < (unsigned)nn) {
            int slot = sub * nbk + (int)(d >> BSH);
            int p = atomicAdd(&bcur[slot], 1);
            if (p < SCAP) ebuf[(size_t)slot * SCAP + p] = (s << BSH) | (d & BMSK);
        }
    }
}
__global__ void k_bdeg(const unsigned* ebuf, const int* bcur, int* cnt,
                       int nbk, int nn) {
    __shared__ int lc[64];
    int b = blockIdx.x;
    int t = threadIdx.x;
    lc[t] = 0;
    __syncthreads();
    for (int sub = 0; sub < NSUB; ++sub) {
        int slot = sub * nbk + b;
        int n = bcur[slot];
        if (n > SCAP) n = SCAP;
        const unsigned* eb = ebuf + (size_t)slot * SCAP;
        for (int j = t; j < n; j += 64)
            atomicAdd(&lc[eb[j] & BMSK], 1);
    }
    __syncthreads();
    int node = (b << BSH) + t;
    if (node < nn) cnt[node] = lc[t];
}
__global__ void k_scan1(const int* cnt, int* rowp, int* bsum, float* dis, int nn) {
    __shared__ int s[256];
    int t = threadIdx.x;
    int i = blockIdx.x * 256 + t;
    int v = (i < nn) ? cnt[i] : 0;
    if (i < nn) dis[i] = rsqrtf((float)v + 1.0f);
    s[t] = v;
    __syncthreads();
    for (int off = 1; off < 256; off <<= 1) {
        int u = (t >= off) ? s[t - off] : 0;
        __syncthreads();
        s[t] += u;
        __syncthreads();
    }
    if (i < nn) rowp[i + 1] = s[t];
    if (t == 255) bsum[blockIdx.x] = s[t];
}
__global__ void k_scan2(int* bsum, int nb) {
    __shared__ int s[512];
    int t = threadIdx.x;
    s[t] = (t < nb) ? bsum[t] : 0;
    __syncthreads();
    for (int off = 1; off < 512; off <<= 1) {
        int u = (t >= off) ? s[t - off] : 0;
        __syncthreads();
        s[t] += u;
        __syncthreads();
    }
    if (t < nb) bsum[t] = s[t];
}
__global__ void k_scan3(int* rowp, const int* bsum, int nn) {
    int i = blockIdx.x * 256 + threadIdx.x;
    if (i == 0) rowp[0] = 0;
    if (i < nn) {
        int b = i >> 8;
        if (b > 0) rowp[i + 1] += bsum[b - 1];
    }
}
__global__ void k_fill2(const unsigned* ebuf, const int* bcur, const int* rowp,
                        int* col, int nbk, int nn) {
    __shared__ int lcur[64];
    __shared__ int lrow[64];
    int b = blockIdx.x;
    int t = threadIdx.x;
    int node = (b << BSH) + t;
    lcur[t] = 0;
    lrow[t] = (node < nn) ? rowp[node] : 0;
    __syncthreads();
    for (int sub = 0; sub < NSUB; ++sub) {
        int slot = sub * nbk + b;
        int n = bcur[slot];
        if (n > SCAP) n = SCAP;
        const unsigned* eb = ebuf + (size_t)slot * SCAP;
        for (int j = t; j < n; j += 64) {
            unsigned e = eb[j];
            int loc = (int)(e & BMSK);
            int off = atomicAdd(&lcur[loc], 1);
            col[lrow[loc] + off] = (int)(e >> BSH);
        }
    }
}
__global__ void k_pack(const float* W, _Float16* Wp, int K) {
    int total = (K / 32) * 2048;
    int idx = blockIdx.x * 256 + threadIdx.x;
    if (idx < total) {
        int i = idx & 7;
        int lane = (idx >> 3) & 63;
        int w = (idx >> 9) & 3;
        int kk = idx >> 11;
        int k = kk * 32 + (lane >> 4) * 8 + i;
        int n = w * 16 + (lane & 15);
        Wp[idx] = (_Float16)W[k * 64 + n];
    }
}
// H' = (X @ W) * dis[node]; TIN = float (layer 1) or f16 (layers 2,3)
template <typename TIN>
__global__ void k_mm_mfma(const TIN* X, const _Float16* Wp, _Float16* H,
                          const float* dis, int K) {
    int l = threadIdx.x & 63;
    int w = threadIdx.x >> 6;
    int n0 = blockIdx.x * 16;
    int am = l & 15;
    int kg = l >> 4;
    const TIN* xrow = X + (size_t)(n0 + am) * K + kg * 8;
    f32x4 acc = {0.f, 0.f, 0.f, 0.f};
    for (int kk = 0; kk < K / 32; ++kk) {
        f16x8 a = load_a(xrow + kk * 32);
        f16x8 b = *(const f16x8*)(Wp + ((size_t)(kk * 4 + w) * 64 + l) * 8);
        acc = __builtin_amdgcn_mfma_f32_16x16x32_f16(a, b, acc, 0, 0, 0);
    }
    int dn = w * 16 + (l & 15);
    int dm0 = (l >> 4) * 4;
#pragma unroll
    for (int r = 0; r < 4; ++r) {
        int node = n0 + dm0 + r;
        H[(size_t)node * 64 + dn] = (_Float16)(acc[r] * dis[node]);
    }
}
// O = relu((sum H'[s] + H'[i]) * dis[i] + b); 2 nodes/wave, 4x unroll.
// TOUT = f16 (layers 1,2 -> next mm) or f32 (layer 3 -> pool)
template <typename TOUT>
__global__ void k_agg(const _Float16* H, const int* col, const int* rowp,
                      const float* dis, const float* bias, TOUT* O, int nn) {
    int hw = threadIdx.x >> 5;
    int lane = threadIdx.x & 31;
    int i = blockIdx.x * 8 + hw;
    if (i >= nn) return;
    const unsigned* Hu = (const unsigned*)H;
    int r0 = rowp[i], r1 = rowp[i + 1];
    float a0 = 0.f, a1 = 0.f;
    int j = r0;
    for (; j + 4 <= r1; j += 4) {
        int s0 = col[j + 0];
        int s1 = col[j + 1];
        int s2 = col[j + 2];
        int s3 = col[j + 3];
        unsigned u0 = Hu[(size_t)s0 * 32 + lane];
        unsigned u1 = Hu[(size_t)s1 * 32 + lane];
        unsigned u2 = Hu[(size_t)s2 * 32 + lane];
        unsigned u3 = Hu[(size_t)s3 * 32 + lane];
        f16x2 h0 = __builtin_bit_cast(f16x2, u0);
        f16x2 h1 = __builtin_bit_cast(f16x2, u1);
        f16x2 h2 = __builtin_bit_cast(f16x2, u2);
        f16x2 h3 = __builtin_bit_cast(f16x2, u3);
        a0 += (float)h0.x + (float)h1.x + (float)h2.x + (float)h3.x;
        a1 += (float)h0.y + (float)h1.y + (float)h2.y + (float)h3.y;
    }
    for (; j < r1; ++j) {
        int s = col[j];
        f16x2 h = __builtin_bit_cast(f16x2, Hu[(size_t)s * 32 + lane]);
        a0 += (float)h.x;
        a1 += (float)h.y;
    }
    f16x2 hi = __builtin_bit_cast(f16x2, Hu[(size_t)i * 32 + lane]);
    a0 += (float)hi.x;
    a1 += (float)hi.y;
    float di = dis[i];
    int ch = lane * 2;
    store_o(&O[(size_t)i * 64 + ch],
            fmaxf(a0 * di + bias[ch], 0.f),
            fmaxf(a1 * di + bias[ch + 1], 0.f));
}
// mean-pool: 16 nodes/wave, 4 waves/block; fast path for single-group chunks
__global__ void k_pool(const float* H, const int* batch, float* pool,
                       const int* flag, int nn) {
    int lane = threadIdx.x & 63;
    int w = threadIdx.x >> 6;
    int c0 = (blockIdx.x * 4 + w) * 16;
    if (c0 >= nn) return;
    int f = flag[0];
    int cend = c0 + 16;
    if (cend > nn) cend = nn;
    int g0 = rdi(batch, c0, f) & 63;
    int g1 = rdi(batch, cend - 1, f) & 63;
    if (g0 == g1) {
        float a0 = 0.f, a1 = 0.f, a2 = 0.f, a3 = 0.f;
        for (int i = c0; i + 4 <= cend; i += 4) {
            a0 += H[(size_t)(i + 0) * 64 + lane];
            a1 += H[(size_t)(i + 1) * 64 + lane];
            a2 += H[(size_t)(i + 2) * 64 + lane];
            a3 += H[(size_t)(i + 3) * 64 + lane];
        }
        atomicAdd(&pool[g0 * 64 + lane], (a0 + a1) + (a2 + a3));
        if (lane == 0) atomicAdd(&pool[4096 + g0], (float)(cend - c0));
    } else {
        float acc = 0.f, cf = 0.f;
        int curg = g0;
        for (int i = c0; i < cend; ++i) {
            int g = rdi(batch, i, f) & 63;
            if (g != curg) {
                atomicAdd(&pool[curg * 64 + lane], acc);
                if (lane == 0) atomicAdd(&pool[4096 + curg], cf);
                acc = 0.f; cf = 0.f; curg = g;
            }
            acc += H[(size_t)i * 64 + lane];
            cf += 1.f;
        }
        atomicAdd(&pool[curg * 64 + lane], acc);
        if (lane == 0) atomicAdd(&pool[4096 + curg], cf);
    }
}
__global__ void k_mlp(const float* pool, const float* fW1, const float* fb1,
                      const float* fW2, const float* fb2, float* out) {
    __shared__ float w1[2048], w2[512], b1s[32], b2s[16], gm[4096];
    int t = threadIdx.x;
    for (int i = t; i < 2048; i += 256) w1[i] = fW1[i];
    for (int i = t; i < 512; i += 256) w2[i] = fW2[i];
    if (t < 32) b1s[t] = fb1[t];
    if (t < 16) b2s[t] = fb2[t];
    for (int i = t; i < 4096; i += 256) {
        float c = pool[4096 + (i >> 6)];
        gm[i] = pool[i] / ((c < 1.f) ? 1.f : c);
    }
    __syncthreads();
    if (t < 64) {
        float hid[32], lg[16];
        for (int j = 0; j < 32; ++j) {
            float s = b1s[j];
            for (int k = 0; k < 64; ++k) s += gm[t * 64 + k] * w1[k * 32 + j];
            hid[j] = fmaxf(s, 0.f);
        }
        float m = -1e30f;
        for (int j = 0; j < 16; ++j) {
            float s = b2s[j];
            for (int k = 0; k < 32; ++k) s += hid[k] * w2[k * 16 + j];
            lg[j] = s;
            m = fmaxf(m, s);
        }
        float se = 0.f;
        for (int j = 0; j < 16; ++j) se += expf(lg[j] - m);
        float lse = m + logf(se);
        for (int j = 0; j < 16; ++j) out[t * 16 + j] = lg[j] - lse;
    }
}

extern "C" void kernel_launch(void* const* d_in, const int* in_sizes, int n_in,
                              void* d_out, int out_size, void* d_ws, size_t ws_size,
                              hipStream_t stream) {
    (void)in_sizes; (void)n_in; (void)out_size;
    const int nn = 100000, ne = 1600000;
    const int nbk = (nn + 63) / 64;   // 1563 buckets of 64 nodes
    const float* x   = (const float*)d_in[0];
    const int*   ei  = (const int*)d_in[1];
    const int*   bat = (const int*)d_in[2];
    const float* W1  = (const float*)d_in[3];
    const float* b1  = (const float*)d_in[4];
    const float* W2  = (const float*)d_in[5];
    const float* b2  = (const float*)d_in[6];
    const float* W3  = (const float*)d_in[7];
    const float* b3  = (const float*)d_in[8];
    const float* fW1 = (const float*)d_in[9];
    const float* fb1 = (const float*)d_in[10];
    const float* fW2 = (const float*)d_in[11];
    const float* fb2 = (const float*)d_in[12];
    float* out = (float*)d_out;

    char* ws = (char*)d_ws;
    size_t o = 0;
    float*    pool = (float*)(ws + o);    o += 16896;
    int*      bcur = (int*)(ws + o);      o += 50176;
    size_t zints = o / 4;
    int*      cnt  = (int*)(ws + o);      o += 400128;
    int*      rowp = (int*)(ws + o);      o += 400384;
    int*      bsum = (int*)(ws + o);      o += 2048;
    float*    dis  = (float*)(ws + o);    o += 400128;
    int*      flag = (int*)(ws + o);      o += 256;
    _Float16* Wp1  = (_Float16*)(ws + o); o += 16384;
    _Float16* Wp2  = (_Float16*)(ws + o); o += 8192;
    _Float16* Wp3  = (_Float16*)(ws + o); o += 8192;
    int*      col  = (int*)(ws + o);      o += 6400000;
    unsigned* ebuf = (unsigned*)(ws + o); o += (size_t)NSUB * nbk * SCAP * 4;
    _Float16* A    = (_Float16*)(ws + o); o += 12800000;   // mm out (f16)
    _Float16* Bh   = (_Float16*)(ws + o); o += 12800000;   // agg out layers 1,2
    float*    Bf   = (float*)(ws + o);    o += 25600000;   // agg out layer 3
    if (ws_size < o) {
        k_mark<<<16, 64, 0, stream>>>(out, 150.0f);
        return;
    }

    int eb = (ne + 255) / 256, nb = (nn + 255) / 256;
    int mmb = nn / 16;
    int aggb = (nn + 7) / 8;
    int poolb = (nn + 63) / 64;

    k_detect<<<1, 64, 0, stream>>>(ei, flag);
    k_zero<<<((int)zints + 255) / 256, 256, 0, stream>>>((int*)ws, (int)zints);
    k_bscatter<<<eb, 256, 0, stream>>>(ei, bcur, ebuf, flag, ne, nn, nbk);
    k_bdeg<<<nbk, 64, 0, stream>>>(ebuf, bcur, cnt, nbk, nn);
    k_scan1<<<nb, 256, 0, stream>>>(cnt, rowp, bsum, dis, nn);
    k_scan2<<<1, 512, 0, stream>>>(bsum, nb);
    k_scan3<<<nb, 256, 0, stream>>>(rowp, bsum, nn);
    k_fill2<<<nbk, 64, 0, stream>>>(ebuf, bcur, rowp, col, nbk, nn);

    k_pack<<<32, 256, 0, stream>>>(W1, Wp1, 128);
    k_pack<<<16, 256, 0, stream>>>(W2, Wp2, 64);
    k_pack<<<16, 256, 0, stream>>>(W3, Wp3, 64);

    k_mm_mfma<float><<<mmb, 256, 0, stream>>>(x, Wp1, A, dis, 128);
    k_agg<_Float16><<<aggb, 256, 0, stream>>>(A, col, rowp, dis, b1, Bh, nn);
    k_mm_mfma<_Float16><<<mmb, 256, 0, stream>>>(Bh, Wp2, A, dis, 64);
    k_agg<_Float16><<<aggb, 256, 0, stream>>>(A, col, rowp, dis, b2, Bh, nn);
    k_mm_mfma<_Float16><<<mmb, 256, 0, stream>>>(Bh, Wp3, A, dis, 64);
    k_agg<float><<<aggb, 256, 0, stream>>>(A, col, rowp, dis, b3, Bf, nn);

    k_pool<<<poolb, 256, 0, stream>>>(Bf, bat, pool, flag, nn);
    k_mlp<<<1, 256, 0, stream>>>(pool, fW1, fb1, fW2, fb2, out);
}

// Round 37
// 329.347 us; speedup vs baseline: 1.3770x; 1.1468x over previous
//
#include <hip/hip_runtime.h>

typedef _Float16 f16x8 __attribute__((ext_vector_type(8)));
typedef _Float16 f16x2 __attribute__((ext_vector_type(2)));
typedef float f32x4 __attribute__((ext_vector_type(4)));

#define BSH  10       // 1024-node buckets: 98 buckets
#define BMSK 1023u
#define EPB  4096     // edges per scatter block (16 per thread)
#define ECAP 18432    // bucket capacity: mean 16384 + 16 sigma

__global__ void GraphCNN_48679159333670_kernel() {}

__device__ __forceinline__ int rdi(const int* p, int pos, int f64) {
    return f64 ? p[2 * pos] : p[pos];
}
__device__ __forceinline__ f16x8 load_a(const float* p) {
    const float4* q = (const float4*)p;
    float4 xa = q[0];
    float4 xb = q[1];
    f16x8 a = { (_Float16)xa.x, (_Float16)xa.y, (_Float16)xa.z, (_Float16)xa.w,
                (_Float16)xb.x, (_Float16)xb.y, (_Float16)xb.z, (_Float16)xb.w };
    return a;
}
__device__ __forceinline__ f16x8 load_a(const _Float16* p) {
    return *(const f16x8*)p;
}
__device__ __forceinline__ void store_o(float* p, float a, float b) {
    float2 o; o.x = a; o.y = b;
    *(float2*)p = o;
}
__device__ __forceinline__ void store_o(_Float16* p, float a, float b) {
    f16x2 h; h.x = (_Float16)a; h.y = (_Float16)b;
    *(f16x2*)p = h;
}

__global__ void k_mark(float* out, float v) {
    int i = blockIdx.x * 64 + threadIdx.x;
    if (i < 1024) out[i] = v;
}
__global__ void k_detect(const int* ei, int* flag) {
    if (threadIdx.x == 0) {
        int nz = 0;
        for (int k = 0; k < 256; ++k) nz += (ei[2 * k + 1] != 0);
        flag[0] = (nz == 0);
    }
}
__global__ void k_zero(int* p, int n) {
    int i = blockIdx.x * 256 + threadIdx.x;
    if (i < n) p[i] = 0;
}
// block-aggregated scatter: LDS histogram over 98 buckets -> ONE global
// atomicAdd per (block,bucket) reserving a contiguous range -> writes are
// line-dense runs (~42 entries). Kills the ~8x partial-line amplification.
__global__ void k_bscatter(const int* ei, int* bcur, unsigned* ebuf,
                           const int* flag, int ne, int nn, int nbk) {
    __shared__ int lhist[128];
    __shared__ int lbase[128];
    int t = threadIdx.x;                  // 256
    int base = blockIdx.x * EPB;
    int f = flag[0];
    if (t < 128) lhist[t] = 0;
    __syncthreads();
    unsigned val[16];
    int bk[16];
    int loff[16];
#pragma unroll
    for (int k = 0; k < 16; ++k) {
        int i = base + k * 256 + t;       // coalesced ei reads
        bk[k] = -1;
        if (i < ne) {
            unsigned s = (unsigned)rdi(ei, i, f);
            unsigned d = (unsigned)rdi(ei, ne + i, f);
            if (s < (unsigned)nn && d < (unsigned)nn) {
                bk[k] = (int)(d >> BSH);
                val[k] = (s << BSH) | (d & BMSK);
                loff[k] = atomicAdd(&lhist[bk[k]], 1);
            }
        }
    }
    __syncthreads();
    if (t < nbk) lbase[t] = atomicAdd(&bcur[t], lhist[t]);
    __syncthreads();
#pragma unroll
    for (int k = 0; k < 16; ++k) {
        if (bk[k] >= 0) {
            int pos = lbase[bk[k]] + loff[k];
            if (pos < ECAP) ebuf[(size_t)bk[k] * ECAP + pos] = val[k];
        }
    }
}
// one block (512 thr) per bucket: degree counts in LDS; cnt written dense
__global__ void k_bdeg(const unsigned* ebuf, const int* bcur, int* cnt, int nn) {
    __shared__ int lc[1024];
    int b = blockIdx.x;
    int t = threadIdx.x;                  // 512
    lc[t] = 0;
    lc[t + 512] = 0;
    __syncthreads();
    int n = bcur[b];
    if (n > ECAP) n = ECAP;
    const unsigned* eb = ebuf + (size_t)b * ECAP;
    for (int j = t; j < n; j += 512)
        atomicAdd(&lc[eb[j] & BMSK], 1);
    __syncthreads();
    int node = (b << BSH) + t;
    if (node < nn) cnt[node] = lc[t];
    node += 512;
    if (node < nn) cnt[node] = lc[t + 512];
}
__global__ void k_scan1(const int* cnt, int* rowp, int* bsum, float* dis, int nn) {
    __shared__ int s[256];
    int t = threadIdx.x;
    int i = blockIdx.x * 256 + t;
    int v = (i < nn) ? cnt[i] : 0;
    if (i < nn) dis[i] = rsqrtf((float)v + 1.0f);
    s[t] = v;
    __syncthreads();
    for (int off = 1; off < 256; off <<= 1) {
        int u = (t >= off) ? s[t - off] : 0;
        __syncthreads();
        s[t] += u;
        __syncthreads();
    }
    if (i < nn) rowp[i + 1] = s[t];
    if (t == 255) bsum[blockIdx.x] = s[t];
}
__global__ void k_scan2(int* bsum, int nb) {
    __shared__ int s[512];
    int t = threadIdx.x;
    s[t] = (t < nb) ? bsum[t] : 0;
    __syncthreads();
    for (int off = 1; off < 512; off <<= 1) {
        int u = (t >= off) ? s[t - off] : 0;
        __syncthreads();
        s[t] += u;
        __syncthreads();
    }
    if (t < nb) bsum[t] = s[t];
}
__global__ void k_scan3(int* rowp, const int* bsum, int nn) {
    int i = blockIdx.x * 256 + threadIdx.x;
    if (i == 0) rowp[0] = 0;
    if (i < nn) {
        int b = i >> 8;
        if (b > 0) rowp[i + 1] += bsum[b - 1];
    }
}
// one block (512 thr) per bucket: LDS cursors + row offsets; 32KB hot col window
__global__ void k_fill2(const unsigned* ebuf, const int* bcur, const int* rowp,
                        int* col, int nn) {
    __shared__ int lcur[1024];
    __shared__ int lrow[1024];
    int b = blockIdx.x;
    int t = threadIdx.x;                  // 512
    for (int q = t; q < 1024; q += 512) {
        int node = (b << BSH) + q;
        lcur[q] = 0;
        lrow[q] = (node < nn) ? rowp[node] : 0;
    }
    __syncthreads();
    int n = bcur[b];
    if (n > ECAP) n = ECAP;
    const unsigned* eb = ebuf + (size_t)b * ECAP;
    for (int j = t; j < n; j += 512) {
        unsigned e = eb[j];
        int loc = (int)(e & BMSK);
        int off = atomicAdd(&lcur[loc], 1);
        col[lrow[loc] + off] = (int)(e >> BSH);
    }
}
__global__ void k_pack(const float* W, _Float16* Wp, int K) {
    int total = (K / 32) * 2048;
    int idx = blockIdx.x * 256 + threadIdx.x;
    if (idx < total) {
        int i = idx & 7;
        int lane = (idx >> 3) & 63;
        int w = (idx >> 9) & 3;
        int kk = idx >> 11;
        int k = kk * 32 + (lane >> 4) * 8 + i;
        int n = w * 16 + (lane & 15);
        Wp[idx] = (_Float16)W[k * 64 + n];
    }
}
// H' = (X @ W) * dis[node]; TIN = float (layer 1) or f16 (layers 2,3)
template <typename TIN>
__global__ void k_mm_mfma(const TIN* X, const _Float16* Wp, _Float16* H,
                          const float* dis, int K) {
    int l = threadIdx.x & 63;
    int w = threadIdx.x >> 6;
    int n0 = blockIdx.x * 16;
    int am = l & 15;
    int kg = l >> 4;
    const TIN* xrow = X + (size_t)(n0 + am) * K + kg * 8;
    f32x4 acc = {0.f, 0.f, 0.f, 0.f};
    for (int kk = 0; kk < K / 32; ++kk) {
        f16x8 a = load_a(xrow + kk * 32);
        f16x8 b = *(const f16x8*)(Wp + ((size_t)(kk * 4 + w) * 64 + l) * 8);
        acc = __builtin_amdgcn_mfma_f32_16x16x32_f16(a, b, acc, 0, 0, 0);
    }
    int dn = w * 16 + (l & 15);
    int dm0 = (l >> 4) * 4;
#pragma unroll
    for (int r = 0; r < 4; ++r) {
        int node = n0 + dm0 + r;
        H[(size_t)node * 64 + dn] = (_Float16)(acc[r] * dis[node]);
    }
}
// O = relu((sum H'[s] + H'[i]) * dis[i] + b); 2 nodes/wave, 4x unroll
template <typename TOUT>
__global__ void k_agg(const _Float16* H, const int* col, const int* rowp,
                      const float* dis, const float* bias, TOUT* O, int nn) {
    int hw = threadIdx.x >> 5;
    int lane = threadIdx.x & 31;
    int i = blockIdx.x * 8 + hw;
    if (i >= nn) return;
    const unsigned* Hu = (const unsigned*)H;
    int r0 = rowp[i], r1 = rowp[i + 1];
    float a0 = 0.f, a1 = 0.f;
    int j = r0;
    for (; j + 4 <= r1; j += 4) {
        int s0 = col[j + 0];
        int s1 = col[j + 1];
        int s2 = col[j + 2];
        int s3 = col[j + 3];
        unsigned u0 = Hu[(size_t)s0 * 32 + lane];
        unsigned u1 = Hu[(size_t)s1 * 32 + lane];
        unsigned u2 = Hu[(size_t)s2 * 32 + lane];
        unsigned u3 = Hu[(size_t)s3 * 32 + lane];
        f16x2 h0 = __builtin_bit_cast(f16x2, u0);
        f16x2 h1 = __builtin_bit_cast(f16x2, u1);
        f16x2 h2 = __builtin_bit_cast(f16x2, u2);
        f16x2 h3 = __builtin_bit_cast(f16x2, u3);
        a0 += (float)h0.x + (float)h1.x + (float)h2.x + (float)h3.x;
        a1 += (float)h0.y + (float)h1.y + (float)h2.y + (float)h3.y;
    }
    for (; j < r1; ++j) {
        int s = col[j];
        f16x2 h = __builtin_bit_cast(f16x2, Hu[(size_t)s * 32 + lane]);
        a0 += (float)h.x;
        a1 += (float)h.y;
    }
    f16x2 hi = __builtin_bit_cast(f16x2, Hu[(size_t)i * 32 + lane]);
    a0 += (float)hi.x;
    a1 += (float)hi.y;
    float di = dis[i];
    int ch = lane * 2;
    store_o(&O[(size_t)i * 64 + ch],
            fmaxf(a0 * di + bias[ch], 0.f),
            fmaxf(a1 * di + bias[ch + 1], 0.f));
}
// mean-pool: 16 nodes/wave, 4 waves/block; fast path for single-group chunks
__global__ void k_pool(const float* H, const int* batch, float* pool,
                       const int* flag, int nn) {
    int lane = threadIdx.x & 63;
    int w = threadIdx.x >> 6;
    int c0 = (blockIdx.x * 4 + w) * 16;
    if (c0 >= nn) return;
    int f = flag[0];
    int cend = c0 + 16;
    if (cend > nn) cend = nn;
    int g0 = rdi(batch, c0, f) & 63;
    int g1 = rdi(batch, cend - 1, f) & 63;
    if (g0 == g1) {
        float a0 = 0.f, a1 = 0.f, a2 = 0.f, a3 = 0.f;
        for (int i = c0; i + 4 <= cend; i += 4) {
            a0 += H[(size_t)(i + 0) * 64 + lane];
            a1 += H[(size_t)(i + 1) * 64 + lane];
            a2 += H[(size_t)(i + 2) * 64 + lane];
            a3 += H[(size_t)(i + 3) * 64 + lane];
        }
        atomicAdd(&pool[g0 * 64 + lane], (a0 + a1) + (a2 + a3));
        if (lane == 0) atomicAdd(&pool[4096 + g0], (float)(cend - c0));
    } else {
        float acc = 0.f, cf = 0.f;
        int curg = g0;
        for (int i = c0; i < cend; ++i) {
            int g = rdi(batch, i, f) & 63;
            if (g != curg) {
                atomicAdd(&pool[curg * 64 + lane], acc);
                if (lane == 0) atomicAdd(&pool[4096 + curg], cf);
                acc = 0.f; cf = 0.f; curg = g;
            }
            acc += H[(size_t)i * 64 + lane];
            cf += 1.f;
        }
        atomicAdd(&pool[curg * 64 + lane], acc);
        if (lane == 0) atomicAdd(&pool[4096 + curg], cf);
    }
}
__global__ void k_mlp(const float* pool, const float* fW1, const float* fb1,
                      const float* fW2, const float* fb2, float* out) {
    __shared__ float w1[2048], w2[512], b1s[32], b2s[16], gm[4096];
    int t = threadIdx.x;
    for (int i = t; i < 2048; i += 256) w1[i] = fW1[i];
    for (int i = t; i < 512; i += 256) w2[i] = fW2[i];
    if (t < 32) b1s[t] = fb1[t];
    if (t < 16) b2s[t] = fb2[t];
    for (int i = t; i < 4096; i += 256) {
        float c = pool[4096 + (i >> 6)];
        gm[i] = pool[i] / ((c < 1.f) ? 1.f : c);
    }
    __syncthreads();
    if (t < 64) {
        float hid[32], lg[16];
        for (int j = 0; j < 32; ++j) {
            float s = b1s[j];
            for (int k = 0; k < 64; ++k) s += gm[t * 64 + k] * w1[k * 32 + j];
            hid[j] = fmaxf(s, 0.f);
        }
        float m = -1e30f;
        for (int j = 0; j < 16; ++j) {
            float s = b2s[j];
            for (int k = 0; k < 32; ++k) s += hid[k] * w2[k * 16 + j];
            lg[j] = s;
            m = fmaxf(m, s);
        }
        float se = 0.f;
        for (int j = 0; j < 16; ++j) se += expf(lg[j] - m);
        float lse = m + logf(se);
        for (int j = 0; j < 16; ++j) out[t * 16 + j] = lg[j] - lse;
    }
}

extern "C" void kernel_launch(void* const* d_in, const int* in_sizes, int n_in,
                              void* d_out, int out_size, void* d_ws, size_t ws_size,
                              hipStream_t stream) {
    (void)in_sizes; (void)n_in; (void)out_size;
    const int nn = 100000, ne = 1600000;
    const int nbk = (nn + 1023) >> 10;   // 98 buckets of 1024 nodes
    const float* x   = (const float*)d_in[0];
    const int*   ei  = (const int*)d_in[1];
    const int*   bat = (const int*)d_in[2];
    const float* W1  = (const float*)d_in[3];
    const float* b1  = (const float*)d_in[4];
    const float* W2  = (const float*)d_in[5];
    const float* b2  = (const float*)d_in[6];
    const float* W3  = (const float*)d_in[7];
    const float* b3  = (const float*)d_in[8];
    const float* fW1 = (const float*)d_in[9];
    const float* fb1 = (const float*)d_in[10];
    const float* fW2 = (const float*)d_in[11];
    const float* fb2 = (const float*)d_in[12];
    float* out = (float*)d_out;

    char* ws = (char*)d_ws;
    size_t o = 0;
    float*    pool = (float*)(ws + o);    o += 16896;
    int*      bcur = (int*)(ws + o);      o += 512;       // 98 bucket cursors
    size_t zints = o / 4;
    int*      cnt  = (int*)(ws + o);      o += 400128;
    int*      rowp = (int*)(ws + o);      o += 400384;
    int*      bsum = (int*)(ws + o);      o += 2048;
    float*    dis  = (float*)(ws + o);    o += 400128;
    int*      flag = (int*)(ws + o);      o += 256;
    _Float16* Wp1  = (_Float16*)(ws + o); o += 16384;
    _Float16* Wp2  = (_Float16*)(ws + o); o += 8192;
    _Float16* Wp3  = (_Float16*)(ws + o); o += 8192;
    int*      col  = (int*)(ws + o);      o += 6400000;
    unsigned* ebuf = (unsigned*)(ws + o); o += (size_t)nbk * ECAP * 4;  // 7.2MB
    _Float16* A    = (_Float16*)(ws + o); o += 12800000;
    _Float16* Bh   = (_Float16*)(ws + o); o += 12800000;
    float*    Bf   = (float*)(ws + o);    o += 25600000;
    if (ws_size < o) {
        k_mark<<<16, 64, 0, stream>>>(out, 150.0f);
        return;
    }

    int eb2 = (ne + EPB - 1) / EPB;      // 391 scatter blocks
    int nb = (nn + 255) / 256;
    int mmb = nn / 16;
    int aggb = (nn + 7) / 8;
    int poolb = (nn + 63) / 64;

    k_detect<<<1, 64, 0, stream>>>(ei, flag);
    k_zero<<<((int)zints + 255) / 256, 256, 0, stream>>>((int*)ws, (int)zints);
    k_bscatter<<<eb2, 256, 0, stream>>>(ei, bcur, ebuf, flag, ne, nn, nbk);
    k_bdeg<<<nbk, 512, 0, stream>>>(ebuf, bcur, cnt, nn);
    k_scan1<<<nb, 256, 0, stream>>>(cnt, rowp, bsum, dis, nn);
    k_scan2<<<1, 512, 0, stream>>>(bsum, nb);
    k_scan3<<<nb, 256, 0, stream>>>(rowp, bsum, nn);
    k_fill2<<<nbk, 512, 0, stream>>>(ebuf, bcur, rowp, col, nn);

    k_pack<<<32, 256, 0, stream>>>(W1, Wp1, 128);
    k_pack<<<16, 256, 0, stream>>>(W2, Wp2, 64);
    k_pack<<<16, 256, 0, stream>>>(W3, Wp3, 64);

    k_mm_mfma<float><<<mmb, 256, 0, stream>>>(x, Wp1, A, dis, 128);
    k_agg<_Float16><<<aggb, 256, 0, stream>>>(A, col, rowp, dis, b1, Bh, nn);
    k_mm_mfma<_Float16><<<mmb, 256, 0, stream>>>(Bh, Wp2, A, dis, 64);
    k_agg<_Float16><<<aggb, 256, 0, stream>>>(A, col, rowp, dis, b2, Bh, nn);
    k_mm_mfma<_Float16><<<mmb, 256, 0, stream>>>(Bh, Wp3, A, dis, 64);
    k_agg<float><<<aggb, 256, 0, stream>>>(A, col, rowp, dis, b3, Bf, nn);

    k_pool<<<poolb, 256, 0, stream>>>(Bf, bat, pool, flag, nn);
    k_mlp<<<1, 256, 0, stream>>>(pool, fW1, fb1, fW2, fb2, out);
}

// Round 38
// 301.551 us; speedup vs baseline: 1.5039x; 1.0922x over previous
//
#include <hip/hip_runtime.h>

typedef _Float16 f16x8 __attribute__((ext_vector_type(8)));
typedef _Float16 f16x2 __attribute__((ext_vector_type(2)));
typedef float f32x4 __attribute__((ext_vector_type(4)));

#define BSH  10       // 1024-node buckets: 98 buckets
#define BMSK 1023u
#define EPB  4096     // edges per scatter block (16 per thread)
#define ECAP 18432    // bucket capacity: mean 16384 + 16 sigma

__global__ void GraphCNN_48679159333670_kernel() {}

__device__ __forceinline__ int rdi(const int* p, int pos, int f64) {
    return f64 ? p[2 * pos] : p[pos];
}
__device__ __forceinline__ f16x8 load_a(const float* p) {
    const float4* q = (const float4*)p;
    float4 xa = q[0];
    float4 xb = q[1];
    f16x8 a = { (_Float16)xa.x, (_Float16)xa.y, (_Float16)xa.z, (_Float16)xa.w,
                (_Float16)xb.x, (_Float16)xb.y, (_Float16)xb.z, (_Float16)xb.w };
    return a;
}
__device__ __forceinline__ f16x8 load_a(const _Float16* p) {
    return *(const f16x8*)p;
}
__device__ __forceinline__ void store_o(float* p, float a, float b) {
    float2 o; o.x = a; o.y = b;
    *(float2*)p = o;
}
__device__ __forceinline__ void store_o(_Float16* p, float a, float b) {
    f16x2 h; h.x = (_Float16)a; h.y = (_Float16)b;
    *(f16x2*)p = h;
}

__global__ void k_mark(float* out, float v) {
    int i = blockIdx.x * 64 + threadIdx.x;
    if (i < 1024) out[i] = v;
}
__global__ void k_detect(const int* ei, int* flag) {
    if (threadIdx.x == 0) {
        int nz = 0;
        for (int k = 0; k < 256; ++k) nz += (ei[2 * k + 1] != 0);
        flag[0] = (nz == 0);
    }
}
__global__ void k_zero(int* p, int n) {
    int i = blockIdx.x * 256 + threadIdx.x;
    if (i < n) p[i] = 0;
}
// block-aggregated scatter: LDS histogram -> one global reservation per
// (block,bucket) -> line-dense writes (r37: bscatter 69 -> ~25us)
__global__ void k_bscatter(const int* ei, int* bcur, unsigned* ebuf,
                           const int* flag, int ne, int nn, int nbk) {
    __shared__ int lhist[128];
    __shared__ int lbase[128];
    int t = threadIdx.x;                  // 256
    int base = blockIdx.x * EPB;
    int f = flag[0];
    if (t < 128) lhist[t] = 0;
    __syncthreads();
    unsigned val[16];
    int bk[16];
    int loff[16];
#pragma unroll
    for (int k = 0; k < 16; ++k) {
        int i = base + k * 256 + t;
        bk[k] = -1;
        if (i < ne) {
            unsigned s = (unsigned)rdi(ei, i, f);
            unsigned d = (unsigned)rdi(ei, ne + i, f);
            if (s < (unsigned)nn && d < (unsigned)nn) {
                bk[k] = (int)(d >> BSH);
                val[k] = (s << BSH) | (d & BMSK);
                loff[k] = atomicAdd(&lhist[bk[k]], 1);
            }
        }
    }
    __syncthreads();
    if (t < nbk) lbase[t] = atomicAdd(&bcur[t], lhist[t]);
    __syncthreads();
#pragma unroll
    for (int k = 0; k < 16; ++k) {
        if (bk[k] >= 0) {
            int pos = lbase[bk[k]] + loff[k];
            if (pos < ECAP) ebuf[(size_t)bk[k] * ECAP + pos] = val[k];
        }
    }
}
__global__ void k_bdeg(const unsigned* ebuf, const int* bcur, int* cnt, int nn) {
    __shared__ int lc[1024];
    int b = blockIdx.x;
    int t = threadIdx.x;                  // 512
    lc[t] = 0;
    lc[t + 512] = 0;
    __syncthreads();
    int n = bcur[b];
    if (n > ECAP) n = ECAP;
    const unsigned* eb = ebuf + (size_t)b * ECAP;
    for (int j = t; j < n; j += 512)
        atomicAdd(&lc[eb[j] & BMSK], 1);
    __syncthreads();
    int node = (b << BSH) + t;
    if (node < nn) cnt[node] = lc[t];
    node += 512;
    if (node < nn) cnt[node] = lc[t + 512];
}
__global__ void k_scan1(const int* cnt, int* rowp, int* bsum, float* dis, int nn) {
    __shared__ int s[256];
    int t = threadIdx.x;
    int i = blockIdx.x * 256 + t;
    int v = (i < nn) ? cnt[i] : 0;
    if (i < nn) dis[i] = rsqrtf((float)v + 1.0f);
    s[t] = v;
    __syncthreads();
    for (int off = 1; off < 256; off <<= 1) {
        int u = (t >= off) ? s[t - off] : 0;
        __syncthreads();
        s[t] += u;
        __syncthreads();
    }
    if (i < nn) rowp[i + 1] = s[t];
    if (t == 255) bsum[blockIdx.x] = s[t];
}
__global__ void k_scan2(int* bsum, int nb) {
    __shared__ int s[512];
    int t = threadIdx.x;
    s[t] = (t < nb) ? bsum[t] : 0;
    __syncthreads();
    for (int off = 1; off < 512; off <<= 1) {
        int u = (t >= off) ? s[t - off] : 0;
        __syncthreads();
        s[t] += u;
        __syncthreads();
    }
    if (t < nb) bsum[t] = s[t];
}
__global__ void k_scan3(int* rowp, const int* bsum, int nn) {
    int i = blockIdx.x * 256 + threadIdx.x;
    if (i == 0) rowp[0] = 0;
    if (i < nn) {
        int b = i >> 8;
        if (b > 0) rowp[i + 1] += bsum[b - 1];
    }
}
__global__ void k_fill2(const unsigned* ebuf, const int* bcur, const int* rowp,
                        int* col, int nn) {
    __shared__ int lcur[1024];
    __shared__ int lrow[1024];
    int b = blockIdx.x;
    int t = threadIdx.x;                  // 512
    for (int q = t; q < 1024; q += 512) {
        int node = (b << BSH) + q;
        lcur[q] = 0;
        lrow[q] = (node < nn) ? rowp[node] : 0;
    }
    __syncthreads();
    int n = bcur[b];
    if (n > ECAP) n = ECAP;
    const unsigned* eb = ebuf + (size_t)b * ECAP;
    for (int j = t; j < n; j += 512) {
        unsigned e = eb[j];
        int loc = (int)(e & BMSK);
        int off = atomicAdd(&lcur[loc], 1);
        col[lrow[loc] + off] = (int)(e >> BSH);
    }
}
__global__ void k_pack(const float* W, _Float16* Wp, int K) {
    int total = (K / 32) * 2048;
    int idx = blockIdx.x * 256 + threadIdx.x;
    if (idx < total) {
        int i = idx & 7;
        int lane = (idx >> 3) & 63;
        int w = (idx >> 9) & 3;
        int kk = idx >> 11;
        int k = kk * 32 + (lane >> 4) * 8 + i;
        int n = w * 16 + (lane & 15);
        Wp[idx] = (_Float16)W[k * 64 + n];
    }
}
template <typename TIN>
__global__ void k_mm_mfma(const TIN* X, const _Float16* Wp, _Float16* H,
                          const float* dis, int K) {
    int l = threadIdx.x & 63;
    int w = threadIdx.x >> 6;
    int n0 = blockIdx.x * 16;
    int am = l & 15;
    int kg = l >> 4;
    const TIN* xrow = X + (size_t)(n0 + am) * K + kg * 8;
    f32x4 acc = {0.f, 0.f, 0.f, 0.f};
    for (int kk = 0; kk < K / 32; ++kk) {
        f16x8 a = load_a(xrow + kk * 32);
        f16x8 b = *(const f16x8*)(Wp + ((size_t)(kk * 4 + w) * 64 + l) * 8);
        acc = __builtin_amdgcn_mfma_f32_16x16x32_f16(a, b, acc, 0, 0, 0);
    }
    int dn = w * 16 + (l & 15);
    int dm0 = (l >> 4) * 4;
#pragma unroll
    for (int r = 0; r < 4; ++r) {
        int node = n0 + dm0 + r;
        H[(size_t)node * 64 + dn] = (_Float16)(acc[r] * dis[node]);
    }
}
template <typename TOUT>
__global__ void k_agg(const _Float16* H, const int* col, const int* rowp,
                      const float* dis, const float* bias, TOUT* O, int nn) {
    int hw = threadIdx.x >> 5;
    int lane = threadIdx.x & 31;
    int i = blockIdx.x * 8 + hw;
    if (i >= nn) return;
    const unsigned* Hu = (const unsigned*)H;
    int r0 = rowp[i], r1 = rowp[i + 1];
    float a0 = 0.f, a1 = 0.f;
    int j = r0;
    for (; j + 4 <= r1; j += 4) {
        int s0 = col[j + 0];
        int s1 = col[j + 1];
        int s2 = col[j + 2];
        int s3 = col[j + 3];
        unsigned u0 = Hu[(size_t)s0 * 32 + lane];
        unsigned u1 = Hu[(size_t)s1 * 32 + lane];
        unsigned u2 = Hu[(size_t)s2 * 32 + lane];
        unsigned u3 = Hu[(size_t)s3 * 32 + lane];
        f16x2 h0 = __builtin_bit_cast(f16x2, u0);
        f16x2 h1 = __builtin_bit_cast(f16x2, u1);
        f16x2 h2 = __builtin_bit_cast(f16x2, u2);
        f16x2 h3 = __builtin_bit_cast(f16x2, u3);
        a0 += (float)h0.x + (float)h1.x + (float)h2.x + (float)h3.x;
        a1 += (float)h0.y + (float)h1.y + (float)h2.y + (float)h3.y;
    }
    for (; j < r1; ++j) {
        int s = col[j];
        f16x2 h = __builtin_bit_cast(f16x2, Hu[(size_t)s * 32 + lane]);
        a0 += (float)h.x;
        a1 += (float)h.y;
    }
    f16x2 hi = __builtin_bit_cast(f16x2, Hu[(size_t)i * 32 + lane]);
    a0 += (float)hi.x;
    a1 += (float)hi.y;
    float di = dis[i];
    int ch = lane * 2;
    store_o(&O[(size_t)i * 64 + ch],
            fmaxf(a0 * di + bias[ch], 0.f),
            fmaxf(a1 * di + bias[ch + 1], 0.f));
}
// mean-pool: block owns 64 nodes (4 waves x 16); fast path reduces the 4 wave
// partials in LDS and issues ONE 64-lane atomic set per block (4x fewer
// global atomics than r37's per-wave flush; pool was atomic-serialization-bound)
__global__ void k_pool(const float* H, const int* batch, float* pool,
                       const int* flag, int nn) {
    __shared__ float red[4][64];
    int t = threadIdx.x;
    int lane = t & 63;
    int w = t >> 6;
    int c0 = blockIdx.x * 64;
    if (c0 >= nn) return;
    int f = flag[0];
    int bend = c0 + 64;
    if (bend > nn) bend = nn;
    int gfirst = rdi(batch, c0, f) & 63;
    int glast = rdi(batch, bend - 1, f) & 63;
    int wc0 = c0 + w * 16;
    int wcend = wc0 + 16;
    if (wcend > bend) wcend = bend;
    if (gfirst == glast) {
        // whole block in one group: wave partials -> LDS -> one atomic set
        float a0 = 0.f, a1 = 0.f, a2 = 0.f, a3 = 0.f;
        for (int i = wc0; i + 4 <= wcend; i += 4) {
            a0 += H[(size_t)(i + 0) * 64 + lane];
            a1 += H[(size_t)(i + 1) * 64 + lane];
            a2 += H[(size_t)(i + 2) * 64 + lane];
            a3 += H[(size_t)(i + 3) * 64 + lane];
        }
        red[w][lane] = (a0 + a1) + (a2 + a3);
        __syncthreads();
        if (w == 0) {
            float tot = red[0][lane] + red[1][lane] + red[2][lane] + red[3][lane];
            atomicAdd(&pool[gfirst * 64 + lane], tot);
            if (lane == 0) atomicAdd(&pool[4096 + gfirst], (float)(bend - c0));
        }
    } else if (wc0 < bend) {
        // group boundary inside block: per-wave running-group loop
        float acc = 0.f, cf = 0.f;
        int curg = rdi(batch, wc0, f) & 63;
        for (int i = wc0; i < wcend; ++i) {
            int g = rdi(batch, i, f) & 63;
            if (g != curg) {
                atomicAdd(&pool[curg * 64 + lane], acc);
                if (lane == 0) atomicAdd(&pool[4096 + curg], cf);
                acc = 0.f; cf = 0.f; curg = g;
            }
            acc += H[(size_t)i * 64 + lane];
            cf += 1.f;
        }
        atomicAdd(&pool[curg * 64 + lane], acc);
        if (lane == 0) atomicAdd(&pool[4096 + curg], cf);
    }
}
__global__ void k_mlp(const float* pool, const float* fW1, const float* fb1,
                      const float* fW2, const float* fb2, float* out) {
    __shared__ float w1[2048], w2[512], b1s[32], b2s[16], gm[4096];
    int t = threadIdx.x;
    for (int i = t; i < 2048; i += 256) w1[i] = fW1[i];
    for (int i = t; i < 512; i += 256) w2[i] = fW2[i];
    if (t < 32) b1s[t] = fb1[t];
    if (t < 16) b2s[t] = fb2[t];
    for (int i = t; i < 4096; i += 256) {
        float c = pool[4096 + (i >> 6)];
        gm[i] = pool[i] / ((c < 1.f) ? 1.f : c);
    }
    __syncthreads();
    if (t < 64) {
        float hid[32], lg[16];
        for (int j = 0; j < 32; ++j) {
            float s = b1s[j];
            for (int k = 0; k < 64; ++k) s += gm[t * 64 + k] * w1[k * 32 + j];
            hid[j] = fmaxf(s, 0.f);
        }
        float m = -1e30f;
        for (int j = 0; j < 16; ++j) {
            float s = b2s[j];
            for (int k = 0; k < 32; ++k) s += hid[k] * w2[k * 16 + j];
            lg[j] = s;
            m = fmaxf(m, s);
        }
        float se = 0.f;
        for (int j = 0; j < 16; ++j) se += expf(lg[j] - m);
        float lse = m + logf(se);
        for (int j = 0; j < 16; ++j) out[t * 16 + j] = lg[j] - lse;
    }
}

extern "C" void kernel_launch(void* const* d_in, const int* in_sizes, int n_in,
                              void* d_out, int out_size, void* d_ws, size_t ws_size,
                              hipStream_t stream) {
    (void)in_sizes; (void)n_in; (void)out_size;
    const int nn = 100000, ne = 1600000;
    const int nbk = (nn + 1023) >> 10;   // 98 buckets of 1024 nodes
    const float* x   = (const float*)d_in[0];
    const int*   ei  = (const int*)d_in[1];
    const int*   bat = (const int*)d_in[2];
    const float* W1  = (const float*)d_in[3];
    const float* b1  = (const float*)d_in[4];
    const float* W2  = (const float*)d_in[5];
    const float* b2  = (const float*)d_in[6];
    const float* W3  = (const float*)d_in[7];
    const float* b3  = (const float*)d_in[8];
    const float* fW1 = (const float*)d_in[9];
    const float* fb1 = (const float*)d_in[10];
    const float* fW2 = (const float*)d_in[11];
    const float* fb2 = (const float*)d_in[12];
    float* out = (float*)d_out;

    char* ws = (char*)d_ws;
    size_t o = 0;
    float*    pool = (float*)(ws + o);    o += 16896;
    int*      bcur = (int*)(ws + o);      o += 512;
    size_t zints = o / 4;
    int*      cnt  = (int*)(ws + o);      o += 400128;
    int*      rowp = (int*)(ws + o);      o += 400384;
    int*      bsum = (int*)(ws + o);      o += 2048;
    float*    dis  = (float*)(ws + o);    o += 400128;
    int*      flag = (int*)(ws + o);      o += 256;
    _Float16* Wp1  = (_Float16*)(ws + o); o += 16384;
    _Float16* Wp2  = (_Float16*)(ws + o); o += 8192;
    _Float16* Wp3  = (_Float16*)(ws + o); o += 8192;
    int*      col  = (int*)(ws + o);      o += 6400000;
    unsigned* ebuf = (unsigned*)(ws + o); o += (size_t)nbk * ECAP * 4;
    _Float16* A    = (_Float16*)(ws + o); o += 12800000;
    _Float16* Bh   = (_Float16*)(ws + o); o += 12800000;
    float*    Bf   = (float*)(ws + o);    o += 25600000;
    if (ws_size < o) {
        k_mark<<<16, 64, 0, stream>>>(out, 150.0f);
        return;
    }

    int eb2 = (ne + EPB - 1) / EPB;
    int nb = (nn + 255) / 256;
    int mmb = nn / 16;
    int aggb = (nn + 7) / 8;
    int poolb = (nn + 63) / 64;

    k_detect<<<1, 64, 0, stream>>>(ei, flag);
    k_zero<<<((int)zints + 255) / 256, 256, 0, stream>>>((int*)ws, (int)zints);
    k_bscatter<<<eb2, 256, 0, stream>>>(ei, bcur, ebuf, flag, ne, nn, nbk);
    k_bdeg<<<nbk, 512, 0, stream>>>(ebuf, bcur, cnt, nn);
    k_scan1<<<nb, 256, 0, stream>>>(cnt, rowp, bsum, dis, nn);
    k_scan2<<<1, 512, 0, stream>>>(bsum, nb);
    k_scan3<<<nb, 256, 0, stream>>>(rowp, bsum, nn);
    k_fill2<<<nbk, 512, 0, stream>>>(ebuf, bcur, rowp, col, nn);

    k_pack<<<32, 256, 0, stream>>>(W1, Wp1, 128);
    k_pack<<<16, 256, 0, stream>>>(W2, Wp2, 64);
    k_pack<<<16, 256, 0, stream>>>(W3, Wp3, 64);

    k_mm_mfma<float><<<mmb, 256, 0, stream>>>(x, Wp1, A, dis, 128);
    k_agg<_Float16><<<aggb, 256, 0, stream>>>(A, col, rowp, dis, b1, Bh, nn);
    k_mm_mfma<_Float16><<<mmb, 256, 0, stream>>>(Bh, Wp2, A, dis, 64);
    k_agg<_Float16><<<aggb, 256, 0, stream>>>(A, col, rowp, dis, b2, Bh, nn);
    k_mm_mfma<_Float16><<<mmb, 256, 0, stream>>>(Bh, Wp3, A, dis, 64);
    k_agg<float><<<aggb, 256, 0, stream>>>(A, col, rowp, dis, b3, Bf, nn);

    k_pool<<<poolb, 256, 0, stream>>>(Bf, bat, pool, flag, nn);
    k_mlp<<<1, 256, 0, stream>>>(pool, fW1, fb1, fW2, fb2, out);
}